// Round 1
// baseline (5008.965 us; speedup 1.0000x reference)
//
#include <hip/hip_runtime.h>
#include <hip/hip_bf16.h>
#include <math.h>

// Problem constants
#define NBR 4      // branches
#define BB 8       // batch
#define NAA 128    // N*A
#define T_IN 200   // input T
#define CCH 8      // channels
#define NQ 8       // quantizers
#define NV 8192    // codebook size
#define DD 200     // feature dim (25*8)
#define ROWS 1024  // B*NA per branch

// ---------------- Stage 1: conv1 + GN + GELU + avgpool2 ----------------
// block = (branch, b, group): 4*8*4 = 128 blocks, 256 threads
__global__ __launch_bounds__(256) void k_stage1(
    const float* __restrict__ x,
    const float* __restrict__ w11, const float* __restrict__ w12,
    const float* __restrict__ w13, const float* __restrict__ w14,
    const float* __restrict__ b1, const float* __restrict__ g1,
    const float* __restrict__ be1, float* __restrict__ y1)
{
  const int blk = blockIdx.x;
  const int br = blk >> 5;
  const int b  = (blk >> 2) & 7;
  const int g  = blk & 3;
  const int tid = threadIdx.x;
  const float* w = (br==0) ? w11 : (br==1) ? w12 : (br==2) ? w13 : w14;
  const int K = (br==0) ? 21 : (br==1) ? 15 : (br==2) ? 9 : 5;
  const int pad = (K-1) >> 1;
  const float* xb = x + (size_t)b * NAA * T_IN;

  // pass A: stats over (2 ch, 128 na, 200 t) conv outputs
  double s = 0.0, s2 = 0.0;
  for (int idx = tid; idx < 2*NAA*T_IN; idx += 256) {
    int t  = idx % T_IN;
    int na = (idx / T_IN) & 127;
    int c  = idx / (T_IN*NAA);
    int cg = g*2 + c;
    float acc = b1[br*CCH + cg];
    const float* xr = xb + na*T_IN;
    const float* wr = w + cg*K;
    int k0 = max(0, pad - t), k1 = min(K, T_IN + pad - t);
    for (int k = k0; k < k1; ++k)
      acc = fmaf(wr[k], xr[t + k - pad], acc);
    s += acc; s2 += (double)acc * acc;
  }
  __shared__ double rs[256], rq[256];
  rs[tid] = s; rq[tid] = s2;
  __syncthreads();
  for (int off = 128; off > 0; off >>= 1) {
    if (tid < off) { rs[tid] += rs[tid+off]; rq[tid] += rq[tid+off]; }
    __syncthreads();
  }
  const double cnt = 2.0*NAA*T_IN;
  double mean = rs[0] / cnt;
  double var  = rq[0] / cnt - mean*mean;
  float fm = (float)mean;
  float rstd = (float)(1.0 / sqrt(var + 1e-5));

  // pass B: recompute conv, GN, exact GELU, avgpool k=2 -> T=100
  for (int idx = tid; idx < 2*NAA*100; idx += 256) {
    int tp = idx % 100;
    int na = (idx / 100) & 127;
    int c  = idx / (100*NAA);
    int cg = g*2 + c;
    const float* xr = xb + na*T_IN;
    const float* wr = w + cg*K;
    float bias = b1[br*CCH + cg];
    float gm = g1[br*CCH + cg], bt = be1[br*CCH + cg];
    float u0 = 0.f, u1 = 0.f;
    #pragma unroll
    for (int h = 0; h < 2; ++h) {
      int t = 2*tp + h;
      float acc = bias;
      int k0 = max(0, pad - t), k1 = min(K, T_IN + pad - t);
      for (int k = k0; k < k1; ++k)
        acc = fmaf(wr[k], xr[t + k - pad], acc);
      float xn = (acc - fm) * rstd * gm + bt;
      float gv = 0.5f * xn * (1.0f + erff(xn * 0.70710678118654752440f));
      if (h == 0) u0 = gv; else u1 = gv;
    }
    y1[((((size_t)br*BB + b)*CCH + cg)*NAA + na)*100 + tp] = 0.5f*(u0 + u1);
  }
}

// ---------------- Stage 2: conv2 + GN + GELU + avgpool4 + transpose ----------------
__global__ __launch_bounds__(256) void k_stage2(
    const float* __restrict__ y1,
    const float* __restrict__ w21, const float* __restrict__ w22,
    const float* __restrict__ w23, const float* __restrict__ w24,
    const float* __restrict__ b2, const float* __restrict__ g2,
    const float* __restrict__ be2, float* __restrict__ res)
{
  const int blk = blockIdx.x;
  const int br = blk >> 5;
  const int b  = (blk >> 2) & 7;
  const int g  = blk & 3;
  const int tid = threadIdx.x;
  const float* w = (br==0) ? w21 : (br==1) ? w22 : (br==2) ? w23 : w24;
  const int K = (br==0) ? 9 : (br==1) ? 7 : (br==2) ? 5 : 3;
  const int pad = (K-1) >> 1;
  const float* yb = y1 + ((size_t)br*BB + b)*CCH*NAA*100;

  double s = 0.0, s2 = 0.0;
  for (int idx = tid; idx < 2*NAA*100; idx += 256) {
    int t  = idx % 100;
    int na = (idx / 100) & 127;
    int c  = idx / (100*NAA);
    int cg = g*2 + c;
    float acc = b2[br*CCH + cg];
    int k0 = max(0, pad - t), k1 = min(K, 100 + pad - t);
    for (int cin = 0; cin < CCH; ++cin) {
      const float* yr = yb + (cin*NAA + na)*100;
      const float* wr = w + (cg*CCH + cin)*K;
      for (int k = k0; k < k1; ++k)
        acc = fmaf(wr[k], yr[t + k - pad], acc);
    }
    s += acc; s2 += (double)acc * acc;
  }
  __shared__ double rs[256], rq[256];
  rs[tid] = s; rq[tid] = s2;
  __syncthreads();
  for (int off = 128; off > 0; off >>= 1) {
    if (tid < off) { rs[tid] += rs[tid+off]; rq[tid] += rq[tid+off]; }
    __syncthreads();
  }
  const double cnt = 2.0*NAA*100;
  double mean = rs[0] / cnt;
  double var  = rq[0] / cnt - mean*mean;
  float fm = (float)mean;
  float rstd = (float)(1.0 / sqrt(var + 1e-5));

  // pass B: pooled k=4 -> T=25, write feats transposed [br][b][na][tp*8+c]
  for (int idx = tid; idx < 2*NAA*25; idx += 256) {
    int tp = idx % 25;
    int na = (idx / 25) & 127;
    int c  = idx / (25*NAA);
    int cg = g*2 + c;
    float bias = b2[br*CCH + cg];
    float gm = g2[br*CCH + cg], bt = be2[br*CCH + cg];
    float sum4 = 0.f;
    #pragma unroll
    for (int h = 0; h < 4; ++h) {
      int t = 4*tp + h;
      float acc = bias;
      int k0 = max(0, pad - t), k1 = min(K, 100 + pad - t);
      for (int cin = 0; cin < CCH; ++cin) {
        const float* yr = yb + (cin*NAA + na)*100;
        const float* wr = w + (cg*CCH + cin)*K;
        for (int k = k0; k < k1; ++k)
          acc = fmaf(wr[k], yr[t + k - pad], acc);
      }
      float xn = (acc - fm) * rstd * gm + bt;
      sum4 += 0.5f * xn * (1.0f + erff(xn * 0.70710678118654752440f));
    }
    res[(((size_t)br*BB + b)*NAA + na)*DD + tp*8 + cg] = 0.25f * sum4;
  }
}

// ---------------- codebook squared norms ----------------
// one wave per codeword row
__global__ __launch_bounds__(256) void k_cbnorm(const float* __restrict__ cbs,
                                                float* __restrict__ cbn)
{
  int wid = (int)((blockIdx.x * 256 + threadIdx.x) >> 6);
  int lane = threadIdx.x & 63;
  if (wid >= NBR*NQ*NV) return;
  const float* r = cbs + (size_t)wid * DD;
  float s = 0.f;
  if (lane < 50) {
    float4 c = *(const float4*)(r + 4*lane);
    s = c.x*c.x + c.y*c.y + c.z*c.z + c.w*c.w;
  }
  for (int off = 32; off > 0; off >>= 1) s += __shfl_down(s, off, 64);
  if (lane == 0) cbn[wid] = s;
}

// ---------------- RVQ argmin (partial over a 2048-codeword chunk) ----------------
// grid: 4 branches * 16 row-tiles * 4 chunks = 256 blocks, 256 threads
// per block: 64 rows x 2048 codewords; per-thread 8 rows x 4 cols
__global__ __launch_bounds__(256) void k_argmin(
    const float* __restrict__ cbs, const float* __restrict__ cbn,
    const float* __restrict__ res, float* __restrict__ pmin,
    int* __restrict__ pidx, int q)
{
  __shared__ float sres[64*200];   // 51.2 KB
  __shared__ float scb[128*202];   // 103.4 KB (202-f32 stride: 2-way-max bank pattern)

  const int bid = blockIdx.x;
  const int br = bid >> 6;
  const int rt = (bid >> 2) & 15;
  const int ch = bid & 3;
  const int tid = threadIdx.x;
  const int vlane = tid & 31;
  const int rg = tid >> 5;           // 0..7 -> rows rg*8..rg*8+7
  const int r0 = rt * 64;

  const float* cb = cbs + (size_t)(br*NQ + q) * NV * DD;
  const float* cn = cbn + (size_t)(br*NQ + q) * NV;
  const float* rr = res + ((size_t)br * ROWS + r0) * DD;

  // stage 64 residual rows
  for (int idx = tid; idx < 64*50; idx += 256) {
    int row = idx / 50, f = idx % 50;
    *(float4*)&sres[row*200 + 4*f] = *(const float4*)&rr[(size_t)row*DD + 4*f];
  }

  float bestv[8]; int besti[8];
  #pragma unroll
  for (int m = 0; m < 8; ++m) { bestv[m] = 3.4e38f; besti[m] = 0; }

  const int vchunk0 = ch * 2048;
  for (int vt = 0; vt < 16; ++vt) {
    const int v0 = vchunk0 + vt*128;
    __syncthreads();  // previous tile's reads done (also orders sres staging)
    // stage codebook tile [128][202]
    for (int idx = tid; idx < 128*50; idx += 256) {
      int vv = idx / 50, f = idx % 50;
      float4 c = *(const float4*)&cb[(size_t)(v0+vv)*DD + 4*f];
      float* d = &scb[vv*202 + 4*f];
      *(float2*)d       = make_float2(c.x, c.y);
      *(float2*)(d + 2) = make_float2(c.z, c.w);
    }
    __syncthreads();

    float acc[8][4];
    #pragma unroll
    for (int m = 0; m < 8; ++m)
      #pragma unroll
      for (int j = 0; j < 4; ++j) acc[m][j] = 0.f;

    for (int k4 = 0; k4 < 50; ++k4) {
      float4 a[8];
      #pragma unroll
      for (int m = 0; m < 8; ++m)
        a[m] = *(const float4*)&sres[(rg*8+m)*200 + 4*k4];
      #pragma unroll
      for (int j = 0; j < 4; ++j) {
        const float* cc = &scb[(vlane + 32*j)*202 + 4*k4];
        float2 c01 = *(const float2*)cc;
        float2 c23 = *(const float2*)(cc + 2);
        #pragma unroll
        for (int m = 0; m < 8; ++m) {
          acc[m][j] = fmaf(a[m].x, c01.x, acc[m][j]);
          acc[m][j] = fmaf(a[m].y, c01.y, acc[m][j]);
          acc[m][j] = fmaf(a[m].z, c23.x, acc[m][j]);
          acc[m][j] = fmaf(a[m].w, c23.y, acc[m][j]);
        }
      }
    }
    // finalize distances for this tile; v ascending per thread (ties -> lowest idx)
    #pragma unroll
    for (int j = 0; j < 4; ++j) {
      int vv = vlane + 32*j;
      float n = cn[v0 + vv];
      int vi = v0 + vv;
      #pragma unroll
      for (int m = 0; m < 8; ++m) {
        float dist = fmaf(-2.0f, acc[m][j], n);
        if (dist < bestv[m] || (dist == bestv[m] && vi < besti[m])) {
          bestv[m] = dist; besti[m] = vi;
        }
      }
    }
  }

  __syncthreads();
  // reduce across the 32 vlanes per row, reusing scb as scratch
  float* rv = scb;                      // [64][32]
  int*   ri = (int*)(scb + 64*32);      // [64][32]
  #pragma unroll
  for (int m = 0; m < 8; ++m) {
    rv[(rg*8+m)*32 + vlane] = bestv[m];
    ri[(rg*8+m)*32 + vlane] = besti[m];
  }
  __syncthreads();
  if (tid < 64) {
    float bv = rv[tid*32]; int bi = ri[tid*32];
    for (int l = 1; l < 32; ++l) {
      float v = rv[tid*32 + l]; int i2 = ri[tid*32 + l];
      if (v < bv || (v == bv && i2 < bi)) { bv = v; bi = i2; }
    }
    pmin[((size_t)br*ROWS + r0 + tid)*4 + ch] = bv;
    pidx[((size_t)br*ROWS + r0 + tid)*4 + ch] = bi;
  }
}

// ---------------- RVQ update: combine chunks, gather, subtract, accumulate ----------------
// grid: 4*1024 blocks, 64 threads (1 wave per row)
__global__ __launch_bounds__(64) void k_update(
    const float* __restrict__ cbs, const float* __restrict__ pmin,
    const int* __restrict__ pidx, float* __restrict__ res,
    float* __restrict__ outq, float* __restrict__ outi, int q)
{
  const int bid = blockIdx.x;
  const int br = bid >> 10;
  const int row = bid & 1023;
  const int lane = threadIdx.x;
  int bi = 0;
  if (lane == 0) {
    const float* pv = &pmin[(size_t)bid*4];
    const int*   pi = &pidx[(size_t)bid*4];
    float bv = pv[0]; bi = pi[0];
    for (int c = 1; c < 4; ++c) {
      if (pv[c] < bv || (pv[c] == bv && pi[c] < bi)) { bv = pv[c]; bi = pi[c]; }
    }
    // idxs output [4][8][8][128] as float values
    outi[(((size_t)br*NQ + q)*BB + (row >> 7))*NAA + (row & 127)] = (float)bi;
  }
  bi = __shfl(bi, 0, 64);
  const float* c = cbs + ((size_t)(br*NQ + q)*NV + bi)*DD;
  float* rrow = res  + ((size_t)br*ROWS + row)*DD;
  float* qrow = outq + ((size_t)br*ROWS + row)*DD;
  if (lane < 50) {
    float4 cv = *(const float4*)&c[4*lane];
    float4 r4 = *(const float4*)&rrow[4*lane];
    r4.x -= cv.x; r4.y -= cv.y; r4.z -= cv.z; r4.w -= cv.w;
    *(float4*)&rrow[4*lane] = r4;
    float4 qv;
    if (q == 0) {
      qv = cv;
    } else {
      qv = *(const float4*)&qrow[4*lane];
      qv.x += cv.x; qv.y += cv.y; qv.z += cv.z; qv.w += cv.w;
    }
    *(float4*)&qrow[4*lane] = qv;
  }
}

extern "C" void kernel_launch(void* const* d_in, const int* in_sizes, int n_in,
                              void* d_out, int out_size, void* d_ws, size_t ws_size,
                              hipStream_t stream)
{
  const float* x   = (const float*)d_in[0];
  const float* w11 = (const float*)d_in[1];
  const float* w12 = (const float*)d_in[2];
  const float* w13 = (const float*)d_in[3];
  const float* w14 = (const float*)d_in[4];
  const float* b1  = (const float*)d_in[5];
  const float* g1  = (const float*)d_in[6];
  const float* be1 = (const float*)d_in[7];
  const float* w21 = (const float*)d_in[8];
  const float* w22 = (const float*)d_in[9];
  const float* w23 = (const float*)d_in[10];
  const float* w24 = (const float*)d_in[11];
  const float* b2  = (const float*)d_in[12];
  const float* g2  = (const float*)d_in[13];
  const float* be2 = (const float*)d_in[14];
  const float* cbs = (const float*)d_in[15];

  float* ws = (float*)d_ws;
  float* y1   = ws;                    // 4*8*8*128*100 = 3,276,800 f32
  float* res  = y1 + 3276800;          // 4*8*128*200   =   819,200 f32
  float* cbn  = res + 819200;          // 4*8*8192      =   262,144 f32
  float* pmin = cbn + 262144;          // 4*1024*4      =    16,384 f32
  int*   pidx = (int*)(pmin + 16384);  // 4*1024*4      =    16,384 i32
  // total ws use: ~17.6 MB

  float* outq = (float*)d_out;         // [4][8][128][200]
  float* outi = outq + 819200;         // [4][8][8][128] (float-encoded indices)

  k_stage1<<<128, 256, 0, stream>>>(x, w11, w12, w13, w14, b1, g1, be1, y1);
  k_stage2<<<128, 256, 0, stream>>>(y1, w21, w22, w23, w24, b2, g2, be2, res);
  k_cbnorm<<<65536, 256, 0, stream>>>(cbs, cbn);
  for (int q = 0; q < NQ; ++q) {
    k_argmin<<<256, 256, 0, stream>>>(cbs, cbn, res, pmin, pidx, q);
    k_update<<<4096, 64, 0, stream>>>(cbs, pmin, pidx, res, outq, outi, q);
  }
}

// Round 4
// 1107.709 us; speedup vs baseline: 4.5219x; 4.5219x over previous
//
#include <hip/hip_runtime.h>
#include <hip/hip_bf16.h>
#include <math.h>

// Problem constants
#define NBR 4      // branches
#define BB 8       // batch
#define NAA 128    // N*A
#define T_IN 200   // input T
#define CCH 8      // channels
#define NQ 8       // quantizers
#define NV 8192    // codebook size
#define DD 200     // feature dim (25*8)
#define ROWS 1024  // B*NA per branch
#define KPAD 224   // 7 * 32
#define NKG 28     // KPAD/8 k-groups

typedef __attribute__((ext_vector_type(8))) short short8;
typedef __attribute__((ext_vector_type(4))) float f32x4;

__device__ __forceinline__ int conv_K1(int br) { return (br==0) ? 21 : (br==1) ? 15 : (br==2) ? 9 : 5; }
__device__ __forceinline__ int conv_K2(int br) { return (br==0) ? 9 : (br==1) ? 7 : (br==2) ? 5 : 3; }

__device__ __forceinline__ unsigned short f2bf(float x) {
  unsigned u = __float_as_uint(x);
  unsigned r = (u + 0x7fffu + ((u >> 16) & 1u)) >> 16;
  return (unsigned short)r;
}
__device__ __forceinline__ float bf2f(unsigned short h) {
  return __uint_as_float(((unsigned)h) << 16);
}
__device__ __forceinline__ bool lexlt(float av, int ai, float bv, int bi) {
  return (av < bv) || (av == bv && ai < bi);
}

// ---------------- K1: conv1 stats partials ----------------
__global__ __launch_bounds__(256) void k_conv1_stats(
    const float* __restrict__ x,
    const float* __restrict__ w11, const float* __restrict__ w12,
    const float* __restrict__ w13, const float* __restrict__ w14,
    const float* __restrict__ b1,
    double* __restrict__ partS, double* __restrict__ partQ)
{
  const int bid = blockIdx.x;
  const int br = bid >> 10;
  const int b  = (bid >> 7) & 7;
  const int na = bid & 127;
  const int tid = threadIdx.x;
  const int c  = tid >> 5;
  const int tl = tid & 31;
  const float* w = (br==0) ? w11 : (br==1) ? w12 : (br==2) ? w13 : w14;
  const int K = conv_K1(br);
  const int pad = (K-1) >> 1;

  __shared__ float sx[T_IN];
  if (tid < T_IN) sx[tid] = x[((size_t)b*NAA + na)*T_IN + tid];
  __syncthreads();

  const float* wr = w + c*K;
  const float bias = b1[br*CCH + c];
  double s = 0.0, s2 = 0.0;
  for (int tt = 0; tt < 7; ++tt) {
    int t = tt*32 + tl;
    if (t < T_IN) {
      float acc = bias;
      int k0 = max(0, pad - t), k1 = min(K, T_IN + pad - t);
      for (int k = k0; k < k1; ++k)
        acc = fmaf(wr[k], sx[t + k - pad], acc);
      s += acc; s2 += (double)acc * acc;
    }
  }
  __shared__ double rs[256], rq[256];
  rs[tid] = s; rq[tid] = s2;
  __syncthreads();
  for (int off = 32; off > 0; off >>= 1) {
    if ((tid & 63) < off) { rs[tid] += rs[tid+off]; rq[tid] += rq[tid+off]; }
    __syncthreads();
  }
  if ((tid & 63) == 0) {
    int g = tid >> 6;
    int pi = (((br*BB + b)*4 + g) << 7) + na;
    partS[pi] = rs[tid]; partQ[pi] = rq[tid];
  }
}

// ---------------- stats reduce ----------------
__global__ __launch_bounds__(128) void k_stats_reduce(
    const double* __restrict__ partS, const double* __restrict__ partQ,
    float* __restrict__ stat, double cnt)
{
  const int blk = blockIdx.x;
  const int tid = threadIdx.x;
  __shared__ double rs[128], rq[128];
  rs[tid] = partS[(blk << 7) + tid];
  rq[tid] = partQ[(blk << 7) + tid];
  __syncthreads();
  for (int off = 64; off > 0; off >>= 1) {
    if (tid < off) { rs[tid] += rs[tid+off]; rq[tid] += rq[tid+off]; }
    __syncthreads();
  }
  if (tid == 0) {
    double mean = rs[0] / cnt;
    double var  = rq[0] / cnt - mean*mean;
    stat[blk]       = (float)mean;
    stat[128 + blk] = (float)(1.0 / sqrt(var + 1e-5));
  }
}

// ---------------- K3: conv1 + GN1 + GELU + pool2 -> conv2 raw + stats2 ----------------
__global__ __launch_bounds__(256) void k_mid(
    const float* __restrict__ x,
    const float* __restrict__ w11, const float* __restrict__ w12,
    const float* __restrict__ w13, const float* __restrict__ w14,
    const float* __restrict__ b1, const float* __restrict__ g1,
    const float* __restrict__ be1, const float* __restrict__ stat1,
    const float* __restrict__ w21, const float* __restrict__ w22,
    const float* __restrict__ w23, const float* __restrict__ w24,
    const float* __restrict__ b2,
    float* __restrict__ y2raw,
    double* __restrict__ partS, double* __restrict__ partQ)
{
  const int bid = blockIdx.x;
  const int br = bid >> 10;
  const int b  = (bid >> 7) & 7;
  const int na = bid & 127;
  const int tid = threadIdx.x;
  const int c  = tid >> 5;
  const int tl = tid & 31;
  const float* w1 = (br==0) ? w11 : (br==1) ? w12 : (br==2) ? w13 : w14;
  const float* w2 = (br==0) ? w21 : (br==1) ? w22 : (br==2) ? w23 : w24;
  const int K1 = conv_K1(br), K2 = conv_K2(br);
  const int pad1 = (K1-1) >> 1, pad2 = (K2-1) >> 1;

  __shared__ float sx[T_IN];
  __shared__ float sy[CCH*100];
  if (tid < T_IN) sx[tid] = x[((size_t)b*NAA + na)*T_IN + tid];
  __syncthreads();

  {
    const float* wr = w1 + c*K1;
    const float bias = b1[br*CCH + c];
    const int g = c >> 1;
    const float fm  = stat1[(br*BB + b)*4 + g];
    const float rst = stat1[128 + (br*BB + b)*4 + g];
    const float gm = g1[br*CCH + c], bt = be1[br*CCH + c];
    for (int tt = 0; tt < 4; ++tt) {
      int tp = tt*32 + tl;
      if (tp < 100) {
        float u = 0.f;
        #pragma unroll
        for (int h = 0; h < 2; ++h) {
          int t = 2*tp + h;
          float acc = bias;
          int k0 = max(0, pad1 - t), k1 = min(K1, T_IN + pad1 - t);
          for (int k = k0; k < k1; ++k)
            acc = fmaf(wr[k], sx[t + k - pad1], acc);
          float xn = (acc - fm) * rst * gm + bt;
          u += 0.5f * xn * (1.0f + erff(xn * 0.70710678118654752440f));
        }
        sy[c*100 + tp] = 0.5f * u;
      }
    }
  }
  __syncthreads();

  double s = 0.0, s2 = 0.0;
  {
    const float bias2 = b2[br*CCH + c];
    float* yout = y2raw + ((((size_t)br*BB + b)*CCH + c)*NAA + na)*100;
    for (int tt = 0; tt < 4; ++tt) {
      int t = tt*32 + tl;
      if (t < 100) {
        float acc = bias2;
        int k0 = max(0, pad2 - t), k1 = min(K2, 100 + pad2 - t);
        for (int cin = 0; cin < CCH; ++cin) {
          const float* wrr = w2 + (c*CCH + cin)*K2;
          const float* yr = sy + cin*100;
          for (int k = k0; k < k1; ++k)
            acc = fmaf(wrr[k], yr[t + k - pad2], acc);
        }
        yout[t] = acc;
        s += acc; s2 += (double)acc * acc;
      }
    }
  }
  __shared__ double rs[256], rq[256];
  rs[tid] = s; rq[tid] = s2;
  __syncthreads();
  for (int off = 32; off > 0; off >>= 1) {
    if ((tid & 63) < off) { rs[tid] += rs[tid+off]; rq[tid] += rq[tid+off]; }
    __syncthreads();
  }
  if ((tid & 63) == 0) {
    int g = tid >> 6;
    int pi = (((br*BB + b)*4 + g) << 7) + na;
    partS[pi] = rs[tid]; partQ[pi] = rq[tid];
  }
}

// ---------------- K5: GN2 + GELU + pool4 + transpose -> res ----------------
__global__ __launch_bounds__(256) void k_tail(
    const float* __restrict__ y2raw, const float* __restrict__ g2,
    const float* __restrict__ be2, const float* __restrict__ stat2,
    float* __restrict__ res)
{
  int idx = blockIdx.x * 256 + threadIdx.x;
  int c  = idx & 7;
  int tp = (idx >> 3) % 25;
  int na = (idx / 200) & 127;
  int b  = (idx / 25600) & 7;
  int br = idx / 204800;
  int g = c >> 1;
  float fm  = stat2[(br*BB + b)*4 + g];
  float rst = stat2[128 + (br*BB + b)*4 + g];
  float gm = g2[br*CCH + c], bt = be2[br*CCH + c];
  float4 v = *(const float4*)&y2raw[((((size_t)br*BB + b)*CCH + c)*NAA + na)*100 + 4*tp];
  float sum4 = 0.f;
  #pragma unroll
  for (int h = 0; h < 4; ++h) {
    float xv = (h==0) ? v.x : (h==1) ? v.y : (h==2) ? v.z : v.w;
    float xn = (xv - fm) * rst * gm + bt;
    sum4 += 0.5f * xn * (1.0f + erff(xn * 0.70710678118654752440f));
  }
  res[((size_t)(br*BB + b)*NAA + na)*DD + tp*8 + c] = 0.25f * sum4;
}

// ---------------- codebook squared norms (one wave per codeword) ----------------
__global__ __launch_bounds__(256) void k_cbnorm(const float* __restrict__ cbs,
                                                float* __restrict__ cbn)
{
  int wid = (int)((blockIdx.x * 256 + threadIdx.x) >> 6);
  int lane = threadIdx.x & 63;
  if (wid >= NBR*NQ*NV) return;
  const float* r = cbs + (size_t)wid * DD;
  float s = 0.f;
  if (lane < 50) {
    float4 c = *(const float4*)(r + 4*lane);
    s = c.x*c.x + c.y*c.y + c.z*c.z + c.w*c.w;
  }
  for (int off = 32; off > 0; off >>= 1) s += __shfl_down(s, off, 64);
  if (lane == 0) cbn[wid] = s;
}

// ---------------- cvt: f32 rows -> bf16 hi/lo, k-major-chunk layout ----------------
// layout: [br][NKG][nrows][8] shorts; pads k 200..223 with zeros
__global__ __launch_bounds__(64) void k_cvt(
    const float* __restrict__ src, int src_q_stride_rows, int q,
    int nrows, short* __restrict__ dh, short* __restrict__ dl)
{
  const int blk = blockIdx.x;
  const int br = blk / nrows;
  const int row = blk - br * nrows;
  const int l = threadIdx.x;
  if (l >= 56) return;
  const float* srow = src + ((size_t)(br * src_q_stride_rows + q) * nrows + row) * DD;
  float v[4];
  if (l < 50) {
    float4 f = *(const float4*)&srow[4*l];
    v[0] = f.x; v[1] = f.y; v[2] = f.z; v[3] = f.w;
  } else {
    v[0] = v[1] = v[2] = v[3] = 0.f;
  }
  short h[4], lo[4];
  #pragma unroll
  for (int i = 0; i < 4; ++i) {
    unsigned short hb = f2bf(v[i]);
    h[i] = (short)hb;
    lo[i] = (short)f2bf(v[i] - bf2f(hb));
  }
  int kg = l >> 1, pos = (l & 1) * 4;
  size_t o = (((size_t)br*NKG + kg)*nrows + row)*8 + pos;
  *(short4*)&dh[o] = make_short4(h[0], h[1], h[2], h[3]);
  *(short4*)&dl[o] = make_short4(lo[0], lo[1], lo[2], lo[3]);
}

// ---------------- MFMA approx-distance GEMM + top-2 candidate epilogue ----------------
// grid: 4 br * 8 rowblk * 64 vblk = 2048 blocks, 256 threads (4 waves, wave tile 64x64)
// candidate slots are per (row, vb, wc): each wave owns its own slot (no cross-wave race)
__global__ __launch_bounds__(256) void k_gemm(
    const short* __restrict__ resh, const short* __restrict__ resl,
    const short* __restrict__ cbh, const short* __restrict__ cbl,
    const float* __restrict__ cbn, int q,
    float* __restrict__ candv, int* __restrict__ candi)
{
  __shared__ short Ah[4][128][8], Al[4][128][8];
  __shared__ short Bh[4][128][8], Bl[4][128][8];   // 32 KB total

  const int blk = blockIdx.x;
  const int vb = blk & 63;
  const int rb = (blk >> 6) & 7;
  const int br = blk >> 9;
  const int tid = threadIdx.x;
  const int w = tid >> 6;
  const int l = tid & 63;
  const int wr = w >> 1, wc = w & 1;
  const int kgl = l >> 4, fr = l & 15;

  f32x4 acc[4][4];
  #pragma unroll
  for (int i = 0; i < 4; ++i)
    #pragma unroll
    for (int j = 0; j < 4; ++j)
      acc[i][j] = (f32x4){0.f, 0.f, 0.f, 0.f};

  for (int ks = 0; ks < 7; ++ks) {
    if (ks) __syncthreads();
    #pragma unroll
    for (int t = 0; t < 2; ++t) {
      int c = tid + t*256;
      int kg = c >> 7, r = c & 127;
      size_t srcA = (((size_t)br*NKG + ks*4 + kg)*ROWS + rb*128 + r) * 8;
      size_t srcB = (((size_t)br*NKG + ks*4 + kg)*NV + vb*128 + r) * 8;
      *(int4*)&Ah[kg][r][0] = *(const int4*)&resh[srcA];
      *(int4*)&Al[kg][r][0] = *(const int4*)&resl[srcA];
      *(int4*)&Bh[kg][r][0] = *(const int4*)&cbh[srcB];
      *(int4*)&Bl[kg][r][0] = *(const int4*)&cbl[srcB];
    }
    __syncthreads();

    short8 ah[4], al[4], bh[4], bl[4];
    #pragma unroll
    for (int i = 0; i < 4; ++i) {
      ah[i] = *(const short8*)&Ah[kgl][wr*64 + i*16 + fr][0];
      al[i] = *(const short8*)&Al[kgl][wr*64 + i*16 + fr][0];
    }
    #pragma unroll
    for (int j = 0; j < 4; ++j) {
      bh[j] = *(const short8*)&Bh[kgl][wc*64 + j*16 + fr][0];
      bl[j] = *(const short8*)&Bl[kgl][wc*64 + j*16 + fr][0];
    }
    #pragma unroll
    for (int i = 0; i < 4; ++i)
      #pragma unroll
      for (int j = 0; j < 4; ++j) {
        f32x4 c = acc[i][j];
        c = __builtin_amdgcn_mfma_f32_16x16x32_bf16(ah[i], bh[j], c, 0, 0, 0);
        c = __builtin_amdgcn_mfma_f32_16x16x32_bf16(ah[i], bl[j], c, 0, 0, 0);
        c = __builtin_amdgcn_mfma_f32_16x16x32_bf16(al[i], bh[j], c, 0, 0, 0);
        acc[i][j] = c;
      }
  }

  // epilogue: s = 0.5*||c||^2 - dot ; per (row, 64-col half) top-2 candidates
  const float* cn = cbn + (size_t)(br*NQ + q)*NV;
  float nj[4]; int vgj[4];
  #pragma unroll
  for (int j = 0; j < 4; ++j) {
    vgj[j] = vb*128 + wc*64 + j*16 + fr;
    nj[j] = 0.5f * cn[vgj[j]];
  }
  #pragma unroll
  for (int i = 0; i < 4; ++i) {
    #pragma unroll
    for (int reg = 0; reg < 4; ++reg) {
      float s0 = nj[0] - acc[i][0][reg];
      float s1 = nj[1] - acc[i][1][reg];
      float s2 = nj[2] - acc[i][2][reg];
      float s3 = nj[3] - acc[i][3][reg];
      float a1v, a2v, b1v, b2v; int a1i, a2i, b1i, b2i;
      if (lexlt(s0, vgj[0], s1, vgj[1])) { a1v=s0; a1i=vgj[0]; a2v=s1; a2i=vgj[1]; }
      else                               { a1v=s1; a1i=vgj[1]; a2v=s0; a2i=vgj[0]; }
      if (lexlt(s2, vgj[2], s3, vgj[3])) { b1v=s2; b1i=vgj[2]; b2v=s3; b2i=vgj[3]; }
      else                               { b1v=s3; b1i=vgj[3]; b2v=s2; b2i=vgj[2]; }
      float c1v, c2v; int c1i, c2i;
      if (lexlt(a1v, a1i, b1v, b1i)) {
        c1v = a1v; c1i = a1i;
        if (lexlt(b1v, b1i, a2v, a2i)) { c2v = b1v; c2i = b1i; } else { c2v = a2v; c2i = a2i; }
      } else {
        c1v = b1v; c1i = b1i;
        if (lexlt(a1v, a1i, b2v, b2i)) { c2v = a1v; c2i = a1i; } else { c2v = b2v; c2i = b2i; }
      }
      // butterfly merge across the 16 col-lanes (same kgl group) of this row
      #pragma unroll
      for (int m = 1; m <= 8; m <<= 1) {
        float o1v = __shfl_xor(c1v, m); int o1i = __shfl_xor(c1i, m);
        float o2v = __shfl_xor(c2v, m); int o2i = __shfl_xor(c2i, m);
        float n1v, n2v; int n1i, n2i;
        if (lexlt(c1v, c1i, o1v, o1i)) {
          n1v = c1v; n1i = c1i;
          if (lexlt(o1v, o1i, c2v, c2i)) { n2v = o1v; n2i = o1i; } else { n2v = c2v; n2i = c2i; }
        } else {
          n1v = o1v; n1i = o1i;
          if (lexlt(c1v, c1i, o2v, o2i)) { n2v = c1v; n2i = c1i; } else { n2v = o2v; n2i = o2i; }
        }
        c1v = n1v; c1i = n1i; c2v = n2v; c2i = n2i;
      }
      if (fr == 0) {
        int grow = br*ROWS + rb*128 + wr*64 + i*16 + kgl*4 + reg;
        size_t o = (((size_t)grow*64 + vb)*2 + wc)*2;
        candv[o] = c1v; candv[o+1] = c2v;
        candi[o] = c1i; candi[o+1] = c2i;
      }
    }
  }
}

// ---------------- top-16 select + exact f32 rescore + residual update ----------------
// grid: 4096 blocks (one row), 64 threads; 256 candidates/row, 4 per lane
__global__ __launch_bounds__(64) void k_update2(
    const float* __restrict__ cbs, const float* __restrict__ cbn,
    const float* __restrict__ candv, const int* __restrict__ candi,
    float* __restrict__ res, float* __restrict__ outq,
    float* __restrict__ outi, int q)
{
  const int blk = blockIdx.x;
  const int br = blk >> 10;
  const int row = blk & 1023;
  const int lane = threadIdx.x;

  const float* cv = candv + (size_t)blk * 256;
  const int*   ci = candi + (size_t)blk * 256;
  float4 v4 = *(const float4*)&cv[4*lane];
  int4   i4 = *(const int4*)&ci[4*lane];
  float vv[4] = {v4.x, v4.y, v4.z, v4.w};
  int   ii[4] = {i4.x, i4.y, i4.z, i4.w};
  bool used[4] = {false, false, false, false};

  __shared__ int slist[16];
  for (int t = 0; t < 16; ++t) {
    float av = 3.4e38f; int ai = 0x7fffffff;
    #pragma unroll
    for (int k = 0; k < 4; ++k)
      if (!used[k] && lexlt(vv[k], ii[k], av, ai)) { av = vv[k]; ai = ii[k]; }
    #pragma unroll
    for (int m = 1; m <= 32; m <<= 1) {
      float bv = __shfl_xor(av, m); int bi = __shfl_xor(ai, m);
      if (lexlt(bv, bi, av, ai)) { av = bv; ai = bi; }
    }
    #pragma unroll
    for (int k = 0; k < 4; ++k)
      if (ai == ii[k]) used[k] = true;
    if (lane == 0) slist[t] = ai;
  }
  __syncthreads();

  // exact rescore of 16 candidates: 4-lane group per candidate
  const int g = lane >> 2, kl = lane & 3;
  const int cg = slist[g];
  const float* cbrow = cbs + ((size_t)(br*NQ + q)*NV + cg)*DD;
  const float* rrow0 = res + (size_t)blk*DD;
  float dot = 0.f;
  for (int u = 0; u < 13; ++u) {
    int k4 = kl + 4*u;
    if (k4 < 50) {
      float4 r4 = *(const float4*)&rrow0[4*k4];
      float4 c4 = *(const float4*)&cbrow[4*k4];
      dot = fmaf(r4.x, c4.x, dot);
      dot = fmaf(r4.y, c4.y, dot);
      dot = fmaf(r4.z, c4.z, dot);
      dot = fmaf(r4.w, c4.w, dot);
    }
  }
  dot += __shfl_xor(dot, 1);
  dot += __shfl_xor(dot, 2);
  float dist = fmaf(-2.f, dot, cbn[(size_t)(br*NQ + q)*NV + cg]);

  int bi = 0;
  {
    float bv = 3.4e38f; int bbi = 0x7fffffff;
    for (int gg = 0; gg < 16; ++gg) {
      float dv = __shfl(dist, gg*4);
      int   di = __shfl(cg, gg*4);
      if (lexlt(dv, di, bv, bbi)) { bv = dv; bbi = di; }
    }
    bi = bbi;
  }

  if (lane == 0)
    outi[(((size_t)br*NQ + q)*BB + (row >> 7))*NAA + (row & 127)] = (float)bi;

  const float* c = cbs + ((size_t)(br*NQ + q)*NV + bi)*DD;
  float* rrow = res  + ((size_t)br*ROWS + row)*DD;
  float* qrow = outq + ((size_t)br*ROWS + row)*DD;
  if (lane < 50) {
    float4 cvv = *(const float4*)&c[4*lane];
    float4 r4 = *(const float4*)&rrow[4*lane];
    r4.x -= cvv.x; r4.y -= cvv.y; r4.z -= cvv.z; r4.w -= cvv.w;
    *(float4*)&rrow[4*lane] = r4;
    float4 qv;
    if (q == 0) {
      qv = cvv;
    } else {
      qv = *(const float4*)&qrow[4*lane];
      qv.x += cvv.x; qv.y += cvv.y; qv.z += cvv.z; qv.w += cvv.w;
    }
    *(float4*)&qrow[4*lane] = qv;
  }
}

extern "C" void kernel_launch(void* const* d_in, const int* in_sizes, int n_in,
                              void* d_out, int out_size, void* d_ws, size_t ws_size,
                              hipStream_t stream)
{
  const float* x   = (const float*)d_in[0];
  const float* w11 = (const float*)d_in[1];
  const float* w12 = (const float*)d_in[2];
  const float* w13 = (const float*)d_in[3];
  const float* w14 = (const float*)d_in[4];
  const float* b1  = (const float*)d_in[5];
  const float* g1  = (const float*)d_in[6];
  const float* be1 = (const float*)d_in[7];
  const float* w21 = (const float*)d_in[8];
  const float* w22 = (const float*)d_in[9];
  const float* w23 = (const float*)d_in[10];
  const float* w24 = (const float*)d_in[11];
  const float* b2  = (const float*)d_in[12];
  const float* g2  = (const float*)d_in[13];
  const float* be2 = (const float*)d_in[14];
  const float* cbs = (const float*)d_in[15];

  // workspace layout
  char* wsb = (char*)d_ws;
  double* partS1 = (double*)wsb;                       // 16384 doubles each
  double* partQ1 = partS1 + 16384;
  double* partS2 = partQ1 + 16384;
  double* partQ2 = partS2 + 16384;
  float* fbase = (float*)(partQ2 + 16384);
  float* stat1 = fbase;                                // 256
  float* stat2 = stat1 + 256;                          // 256
  float* y2raw = stat2 + 256;                          // 3,276,800
  float* res   = y2raw + 3276800;                      // 819,200
  float* cbn   = res + 819200;                         // 262,144
  float* candv = cbn + 262144;                         // 1,048,576
  int*   candi = (int*)(candv + 1048576);              // 1,048,576
  short* resh  = (short*)(candi + 1048576);            // 917,504 shorts
  short* resl  = resh + 917504;                        // 917,504
  short* cbh   = resl + 917504;                        // 7,340,032
  short* cbl   = cbh + 7340032;                        // 7,340,032
  // total ~59 MB

  float* outq = (float*)d_out;         // [4][8][128][200]
  float* outi = outq + 819200;         // [4][8][8][128] (float-encoded indices)

  k_cbnorm<<<65536, 256, 0, stream>>>(cbs, cbn);
  k_conv1_stats<<<4096, 256, 0, stream>>>(x, w11, w12, w13, w14, b1, partS1, partQ1);
  k_stats_reduce<<<128, 128, 0, stream>>>(partS1, partQ1, stat1, 2.0*NAA*T_IN);
  k_mid<<<4096, 256, 0, stream>>>(x, w11, w12, w13, w14, b1, g1, be1, stat1,
                                  w21, w22, w23, w24, b2, y2raw, partS2, partQ2);
  k_stats_reduce<<<128, 128, 0, stream>>>(partS2, partQ2, stat2, 2.0*NAA*100);
  k_tail<<<3200, 256, 0, stream>>>(y2raw, g2, be2, stat2, res);

  for (int q = 0; q < NQ; ++q) {
    k_cvt<<<NBR*NV, 64, 0, stream>>>(cbs, NQ, q, NV, cbh, cbl);
    k_cvt<<<NBR*ROWS, 64, 0, stream>>>(res, 1, 0, ROWS, resh, resl);
    k_gemm<<<2048, 256, 0, stream>>>(resh, resl, cbh, cbl, cbn, q, candv, candi);
    k_update2<<<4096, 64, 0, stream>>>(cbs, cbn, candv, candi, res, outq, outi, q);
  }
}